// Round 4
// baseline (283.888 us; speedup 1.0000x reference)
//
#include <hip/hip_runtime.h>
#include <hip/hip_bf16.h>

#define BB 2
#define NN 65536
#define DP 64
#define DM 128
#define SCALEF 0.08838834764831845f   // 1/sqrt(128)

typedef __attribute__((ext_vector_type(8))) short short8v;
typedef __attribute__((ext_vector_type(4))) float float4v;

// ---------- helpers ----------
__device__ __forceinline__ unsigned short f2bf(float f) {   // RNE f32->bf16
  unsigned u = __float_as_uint(f);
  u += 0x7FFFu + ((u >> 16) & 1u);
  return (unsigned short)(u >> 16);
}
__device__ __forceinline__ float bf2f(unsigned short h) {
  return __uint_as_float(((unsigned)h) << 16);
}

// ---------- K0: transpose+convert weights to bf16 [n][k]; wqk = wq-wk; zero sums ----------
__global__ __launch_bounds__(256) void k0_kernel(
    const float* __restrict__ wq, const float* __restrict__ wk,
    const float* __restrict__ fc1_w, const float* __restrict__ fc2_w,
    const float* __restrict__ d2_w, const float* __restrict__ g1_w,
    const float* __restrict__ g2_w, const float* __restrict__ wv_w,
    float* __restrict__ sums,
    short* __restrict__ d2t, short* __restrict__ fc1t, short* __restrict__ wqkt,
    short* __restrict__ g1t, short* __restrict__ g2t, short* __restrict__ wvt,
    short* __restrict__ fc2t) {
  int t = threadIdx.x, bi = blockIdx.x;
  if (bi == 0) sums[t] = 0.f;                  // sums[BB*DM]
  int mat = bi >> 5, blk = bi & 31;
  if (mat == 1) {                              // fc1: [64][128] -> fc1t[128][64]
    int i = blk * 256 + t;
    int n = i >> 6, k = i & 63;
    fc1t[n * 64 + k] = (short)f2bf(fc1_w[k * 128 + n]);
  } else if (mat == 6) {                       // fc2: [128][64] -> fc2t[64][128]
    int i = blk * 256 + t;
    int n = i >> 7, k = i & 127;
    fc2t[n * 128 + k] = (short)f2bf(fc2_w[k * 64 + n]);
  } else {
    const float* src = (mat == 0) ? d2_w : (mat == 2) ? wq : (mat == 3) ? g1_w
                     : (mat == 4) ? g2_w : wv_w;
    short* dst = (mat == 0) ? d2t : (mat == 2) ? wqkt : (mat == 3) ? g1t
               : (mat == 4) ? g2t : wvt;
#pragma unroll
    for (int j = 0; j < 2; ++j) {
      int i = blk * 512 + t + j * 256;
      int n = i >> 7, k = i & 127;
      float v = src[k * 128 + n];
      if (mat == 2) v -= wk[k * 128 + n];
      dst[n * 128 + k] = (short)f2bf(v);
    }
  }
}

// ---------- register-resident B fragments (weights L2-hot) ----------
template<int K>
__device__ __forceinline__ void loadB(const short* __restrict__ Wt,
                                      int wid, int col, int quad, short8v b[2][4]) {
#pragma unroll
  for (int nt = 0; nt < 2; ++nt)
#pragma unroll
    for (int kt = 0; kt < K / 32; ++kt)
      b[nt][kt] = *(const short8v*)(Wt + (wid * 32 + nt * 16 + col) * K + kt * 32 + quad * 8);
}

// M=32 tile: acc[2][2], A in LDS [32][136]
template<int K>
__device__ __forceinline__ void gemm_compute(const short* __restrict__ A,
                                             const short8v b[2][4],
                                             int col, int quad, float4v acc[2][2]) {
#pragma unroll
  for (int kt = 0; kt < K / 32; ++kt) {
#pragma unroll
    for (int mt = 0; mt < 2; ++mt) {
      short8v a = *(const short8v*)(A + (mt * 16 + col) * 136 + kt * 32 + quad * 8);
      acc[mt][0] = __builtin_amdgcn_mfma_f32_16x16x32_bf16(a, b[0][kt], acc[mt][0], 0, 0, 0);
      acc[mt][1] = __builtin_amdgcn_mfma_f32_16x16x32_bf16(a, b[1][kt], acc[mt][1], 0, 0, 0);
    }
  }
}

__device__ __forceinline__ void store_tile(short* __restrict__ dst,
                                           const float4v acc[2][2],
                                           int wid, int col, int quad,
                                           float b0, float b1, bool do_relu) {
#pragma unroll
  for (int mt = 0; mt < 2; ++mt)
#pragma unroll
    for (int nt = 0; nt < 2; ++nt) {
      float bias = nt ? b1 : b0;
#pragma unroll
      for (int r = 0; r < 4; ++r) {
        float v = acc[mt][nt][r] + bias;
        if (do_relu) v = fmaxf(v, 0.f);
        dst[(mt * 16 + quad * 4 + r) * 136 + wid * 32 + nt * 16 + col] = (short)f2bf(v);
      }
    }
}

#define ZERO_ACC(acc) \
  _Pragma("unroll") for (int mt = 0; mt < 2; ++mt) \
  _Pragma("unroll") for (int nt = 0; nt < 2; ++nt) \
  _Pragma("unroll") for (int r = 0; r < 4; ++r) acc[mt][nt][r] = 0.f;

// ---------- K1: full chain; writes E=exp(l*SCALE) bf16 + G bf16 + partial sums ----------
// M=32 rows/block; small LDS (17.4 KB) -> 5+ blocks/CU for latency hiding (TLP).
__global__ __launch_bounds__(256, 5) void k1_kernel(
    const float* __restrict__ xyz, const float* __restrict__ features,
    const short* __restrict__ fc1t, const float* __restrict__ fc1_b,
    const float* __restrict__ d1_w, const float* __restrict__ d1_b,
    const short* __restrict__ d2t, const float* __restrict__ d2_b,
    const short* __restrict__ g1t, const float* __restrict__ g1_b,
    const short* __restrict__ g2t, const float* __restrict__ g2_b,
    const short* __restrict__ wqkt, const short* __restrict__ wvt,
    unsigned short* __restrict__ Ebf, unsigned short* __restrict__ Gbf,
    float* __restrict__ sums) {
  __shared__ __align__(16) short As[32 * 136];   // R -> F -> T -> H
  __shared__ __align__(16) short Xs[32 * 136];   // xyz scratch, then X (persists)

  const int tid = threadIdx.x;
  const int wid = tid >> 6, lane = tid & 63;
  const int col = lane & 15, quad = lane >> 4;
  const long long p0 = (long long)blockIdx.x * 32;
  const int bi = (int)(p0 >> 16);

  short8v b[2][4];
  loadB<128>(d2t, wid, col, quad, b);            // prefetch d2 B over xyz/R phase

  float* xf = (float*)Xs;
  if (tid < 96) xf[tid] = xyz[p0 * 3 + tid];
  __syncthreads();                               // (1) xyz visible

  // R = relu(xyz @ d1 + d1_b) -> As (bf16); 32 rows
  {
    const int tn = tid & 31, tm = tid >> 5;
    const int c4 = tn * 4, pbase = tm * 4;
    float4 w0 = *(const float4*)(d1_w + c4);
    float4 w1 = *(const float4*)(d1_w + 128 + c4);
    float4 w2 = *(const float4*)(d1_w + 256 + c4);
    float4 bb = *(const float4*)(d1_b + c4);
#pragma unroll
    for (int p = 0; p < 4; ++p) {
      float x0 = xf[(pbase + p) * 3 + 0];
      float x1 = xf[(pbase + p) * 3 + 1];
      float x2 = xf[(pbase + p) * 3 + 2];
      short4 rr;
      rr.x = (short)f2bf(fmaxf(0.f, fmaf(x0, w0.x, fmaf(x1, w1.x, fmaf(x2, w2.x, bb.x)))));
      rr.y = (short)f2bf(fmaxf(0.f, fmaf(x0, w0.y, fmaf(x1, w1.y, fmaf(x2, w2.y, bb.y)))));
      rr.z = (short)f2bf(fmaxf(0.f, fmaf(x0, w0.z, fmaf(x1, w1.z, fmaf(x2, w2.z, bb.z)))));
      rr.w = (short)f2bf(fmaxf(0.f, fmaf(x0, w0.w, fmaf(x1, w1.w, fmaf(x2, w2.w, bb.w)))));
      *(short4*)(As + (pbase + p) * 136 + c4) = rr;
    }
  }
  __syncthreads();                               // (2) R written

  const int ch0 = wid * 32 + col, ch1 = ch0 + 16;
  float4v pe[2][2], acc[2][2];

  // PE = R @ d2 + d2_b (regs)
  ZERO_ACC(acc)
  gemm_compute<128>(As, b, col, quad, acc);
  {
    float b0 = d2_b[ch0], b1 = d2_b[ch1];
#pragma unroll
    for (int mt = 0; mt < 2; ++mt)
#pragma unroll
      for (int r = 0; r < 4; ++r) {
        pe[mt][0][r] = acc[mt][0][r] + b0;
        pe[mt][1][r] = acc[mt][1][r] + b1;
      }
  }
  loadB<64>(fc1t, wid, col, quad, b);
  __syncthreads();                               // (3) d2's As readers done

  // F -> As (bf16), 32x64
#pragma unroll
  for (int j = 0; j < 2; ++j) {
    int c = tid + j * 256;
    float4 f = *(const float4*)(features + p0 * 64 + (long long)c * 4);
    int row = c >> 4, cp = (c & 15) * 4;
    short4 s;
    s.x = (short)f2bf(f.x); s.y = (short)f2bf(f.y);
    s.z = (short)f2bf(f.z); s.w = (short)f2bf(f.w);
    *(short4*)(As + row * 136 + cp) = s;
  }
  __syncthreads();                               // (4) F written

  // X = F @ fc1 + fc1_b -> Xs
  ZERO_ACC(acc)
  gemm_compute<64>(As, b, col, quad, acc);
  store_tile(Xs, acc, wid, col, quad, fc1_b[ch0], fc1_b[ch1], false);
  loadB<128>(wqkt, wid, col, quad, b);
  __syncthreads();                               // (5) Xs written; fc1's As reads done

  // T = PE + X @ wqk -> As
#pragma unroll
  for (int mt = 0; mt < 2; ++mt)
#pragma unroll
    for (int nt = 0; nt < 2; ++nt)
#pragma unroll
      for (int r = 0; r < 4; ++r) acc[mt][nt][r] = pe[mt][nt][r];
  gemm_compute<128>(Xs, b, col, quad, acc);
  store_tile(As, acc, wid, col, quad, 0.f, 0.f, false);
  loadB<128>(g1t, wid, col, quad, b);
  __syncthreads();                               // (6) T written

  // H = relu(T @ g1 + g1_b) -> As (in place)
  ZERO_ACC(acc)
  gemm_compute<128>(As, b, col, quad, acc);
  __syncthreads();                               // (7) T readers done
  store_tile(As, acc, wid, col, quad, g1_b[ch0], g1_b[ch1], true);
  loadB<128>(g2t, wid, col, quad, b);
  __syncthreads();                               // (8) H written

  // L = H @ g2 + g2_b; E = exp(L*SCALE) -> global bf16; per-channel partial sums
  ZERO_ACC(acc)
  gemm_compute<128>(As, b, col, quad, acc);
  {
    short8v b2[2][4];
    loadB<128>(wvt, wid, col, quad, b2);         // prefetch wv B under exp/store phase
    float b0 = g2_b[ch0], b1 = g2_b[ch1];
    float s0 = 0.f, s1 = 0.f;
#pragma unroll
    for (int mt = 0; mt < 2; ++mt)
#pragma unroll
      for (int r = 0; r < 4; ++r) {
        long long row = p0 + mt * 16 + quad * 4 + r;
        float e0 = __expf((acc[mt][0][r] + b0) * SCALEF);
        float e1 = __expf((acc[mt][1][r] + b1) * SCALEF);
        Ebf[row * DM + ch0] = f2bf(e0);
        Ebf[row * DM + ch1] = f2bf(e1);
        s0 += e0; s1 += e1;
      }
    s0 += __shfl_xor(s0, 16, 64); s0 += __shfl_xor(s0, 32, 64);
    s1 += __shfl_xor(s1, 16, 64); s1 += __shfl_xor(s1, 32, 64);
    if (quad == 0) {
      atomicAdd(&sums[bi * DM + ch0], s0);
      atomicAdd(&sums[bi * DM + ch1], s1);
    }

    // G = PE + X @ wv -> global bf16 (Xs unchanged since X: no barrier needed)
#pragma unroll
    for (int mt = 0; mt < 2; ++mt)
#pragma unroll
      for (int nt = 0; nt < 2; ++nt)
#pragma unroll
        for (int r = 0; r < 4; ++r) acc[mt][nt][r] = pe[mt][nt][r];
    gemm_compute<128>(Xs, b2, col, quad, acc);
#pragma unroll
    for (int mt = 0; mt < 2; ++mt)
#pragma unroll
      for (int r = 0; r < 4; ++r) {
        long long row = p0 + mt * 16 + quad * 4 + r;
        Gbf[row * DM + ch0] = f2bf(acc[mt][0][r]);
        Gbf[row * DM + ch1] = f2bf(acc[mt][1][r]);
      }
  }
}

// ---------- K3: attn = E/sum; res = bf16(attn*G) @ fc2 + fc2_b + features ----------
// M=32 rows/block. Gbf aliases the res output region byte-exactly; each block reads
// its own 32 rows before the barrier and overwrites them after.
__global__ __launch_bounds__(256, 5) void k3_kernel(
    const unsigned short* __restrict__ Ebf, float* __restrict__ out_attn,
    float* __restrict__ out_res, const unsigned short* __restrict__ Gbf,
    const float* __restrict__ sums,
    const short* __restrict__ fc2t, const float* __restrict__ fc2_b,
    const float* __restrict__ features) {
  __shared__ __align__(16) short Ys[32 * 136];   // bf16 Y; reused as float[32][68] for res
  const int tid = threadIdx.x;
  const long long p0 = (long long)blockIdx.x * 32;
  const int bi = (int)(p0 >> 16);

  // Phase A: streaming normalize (ushort8/float4, fully coalesced)
  {
    const int tn = tid & 15, tm = tid >> 4;
    const int c8 = tn * 8;
    float4 sv0 = *(const float4*)(sums + bi * DM + c8);
    float4 sv1 = *(const float4*)(sums + bi * DM + c8 + 4);
    float4 r0, r1;
    r0.x = 1.f / sv0.x; r0.y = 1.f / sv0.y; r0.z = 1.f / sv0.z; r0.w = 1.f / sv0.w;
    r1.x = 1.f / sv1.x; r1.y = 1.f / sv1.y; r1.z = 1.f / sv1.z; r1.w = 1.f / sv1.w;
#pragma unroll
    for (int it = 0; it < 2; ++it) {
      int row = tm + it * 16;
      long long idx = (p0 + row) * DM + c8;
      short8v e8 = *(const short8v*)(Ebf + idx);
      short8v g8 = *(const short8v*)(Gbf + idx);
      float a[8];
      a[0] = bf2f((unsigned short)e8[0]) * r0.x; a[1] = bf2f((unsigned short)e8[1]) * r0.y;
      a[2] = bf2f((unsigned short)e8[2]) * r0.z; a[3] = bf2f((unsigned short)e8[3]) * r0.w;
      a[4] = bf2f((unsigned short)e8[4]) * r1.x; a[5] = bf2f((unsigned short)e8[5]) * r1.y;
      a[6] = bf2f((unsigned short)e8[6]) * r1.z; a[7] = bf2f((unsigned short)e8[7]) * r1.w;
      float4 a0 = {a[0], a[1], a[2], a[3]};
      float4 a1 = {a[4], a[5], a[6], a[7]};
      *(float4*)(out_attn + idx) = a0;
      *(float4*)(out_attn + idx + 4) = a1;
      short8v y;
#pragma unroll
      for (int q = 0; q < 8; ++q)
        y[q] = (short)f2bf(a[q] * bf2f((unsigned short)g8[q]));
      *(short8v*)(Ys + row * 136 + c8) = y;
    }
  }

  const int wid = tid >> 6, lane = tid & 63;
  const int col = lane & 15, quad = lane >> 4;
  const int n = wid * 16 + col;
  short8v bw[4];
#pragma unroll
  for (int kt = 0; kt < 4; ++kt)
    bw[kt] = *(const short8v*)(fc2t + n * DM + kt * 32 + quad * 8);
  __syncthreads();                               // Y visible

  float4v acc[2];
#pragma unroll
  for (int mt = 0; mt < 2; ++mt)
#pragma unroll
    for (int r = 0; r < 4; ++r) acc[mt][r] = 0.f;
#pragma unroll
  for (int kt = 0; kt < 4; ++kt)
#pragma unroll
    for (int mt = 0; mt < 2; ++mt) {
      short8v a = *(const short8v*)(Ys + (mt * 16 + col) * 136 + kt * 32 + quad * 8);
      acc[mt] = __builtin_amdgcn_mfma_f32_16x16x32_bf16(a, bw[kt], acc[mt], 0, 0, 0);
    }
  __syncthreads();                               // all Ys reads done
  float* yf = (float*)Ys;                        // reuse as float[32][68]
  float bb = fc2_b[n];
#pragma unroll
  for (int mt = 0; mt < 2; ++mt)
#pragma unroll
    for (int r = 0; r < 4; ++r)
      yf[(mt * 16 + quad * 4 + r) * 68 + n] = acc[mt][r] + bb;
  __syncthreads();                               // res tile in LDS

  // coalesced res store + features residual (float4)
#pragma unroll
  for (int it = 0; it < 2; ++it) {
    int idx = tid + it * 256;
    int row = idx >> 4, ch = idx & 15;
    float4 v = *(const float4*)(yf + row * 68 + ch * 4);
    float4 ft = *(const float4*)(features + (p0 + row) * DP + ch * 4);
    float4 o;
    o.x = v.x + ft.x; o.y = v.y + ft.y; o.z = v.z + ft.z; o.w = v.w + ft.w;
    *(float4*)(out_res + (p0 + row) * DP + ch * 4) = o;
  }
}

extern "C" void kernel_launch(void* const* d_in, const int* in_sizes, int n_in,
                              void* d_out, int out_size, void* d_ws, size_t ws_size,
                              hipStream_t stream) {
  const float* xyz      = (const float*)d_in[0];
  const float* features = (const float*)d_in[1];
  const float* fc1_w    = (const float*)d_in[2];
  const float* fc1_b    = (const float*)d_in[3];
  const float* fc2_w    = (const float*)d_in[4];
  const float* fc2_b    = (const float*)d_in[5];
  const float* d1_w     = (const float*)d_in[6];
  const float* d1_b     = (const float*)d_in[7];
  const float* d2_w     = (const float*)d_in[8];
  const float* d2_b     = (const float*)d_in[9];
  const float* g1_w     = (const float*)d_in[10];
  const float* g1_b     = (const float*)d_in[11];
  const float* g2_w     = (const float*)d_in[12];
  const float* g2_b     = (const float*)d_in[13];
  const float* wq       = (const float*)d_in[14];
  const float* wk       = (const float*)d_in[15];
  const float* wv       = (const float*)d_in[16];

  float* out_res  = (float*)d_out;
  float* out_attn = out_res + (long long)BB * NN * DP;

  float* sums = (float*)d_ws;                          // [256]
  short* d2t  = (short*)(sums + 256);                  // 128*128
  short* fc1t = d2t + 16384;                           // 128*64
  short* wqkt = fc1t + 8192;                           // 128*128
  short* g1t  = wqkt + 16384;
  short* g2t  = g1t + 16384;
  short* wvt  = g2t + 16384;
  short* fc2t = wvt + 16384;                           // 64*128
  unsigned short* Ebf = (unsigned short*)(fc2t + 8192);   // [BB*NN*DM] bf16 (~33.5 MB)
  unsigned short* Gbf = (unsigned short*)d_out;        // aliases res region (byte-exact)

  hipLaunchKernelGGL(k0_kernel, dim3(224), dim3(256), 0, stream,
                     wq, wk, fc1_w, fc2_w, d2_w, g1_w, g2_w, wv,
                     sums, d2t, fc1t, wqkt, g1t, g2t, wvt, fc2t);
  hipLaunchKernelGGL(k1_kernel, dim3((BB * NN) / 32), dim3(256), 0, stream,
                     xyz, features, fc1t, fc1_b, d1_w, d1_b, d2t, d2_b,
                     g1t, g1_b, g2t, g2_b, wqkt, wvt, Ebf, Gbf, sums);
  hipLaunchKernelGGL(k3_kernel, dim3((BB * NN) / 32), dim3(256), 0, stream,
                     Ebf, out_attn, out_res, Gbf, sums, fc2t, fc2_b, features);
}

// Round 5
// 234.082 us; speedup vs baseline: 1.2128x; 1.2128x over previous
//
#include <hip/hip_runtime.h>
#include <hip/hip_bf16.h>

#define BB 2
#define NN 65536
#define DP 64
#define DM 128
#define SCALEF 0.08838834764831845f   // 1/sqrt(128)

typedef __attribute__((ext_vector_type(8))) short short8v;
typedef __attribute__((ext_vector_type(4))) float float4v;

#define K1_GRID 512
#define K1_ITERS 8           // tiles of 32 points per block (contiguous => one batch/block)
#define K3_GRID 512
#define K3_ITERS 8

// ---------- helpers ----------
__device__ __forceinline__ unsigned short f2bf(float f) {   // RNE f32->bf16
  unsigned u = __float_as_uint(f);
  u += 0x7FFFu + ((u >> 16) & 1u);
  return (unsigned short)(u >> 16);
}
__device__ __forceinline__ float bf2f(unsigned short h) {
  return __uint_as_float(((unsigned)h) << 16);
}

// ---------- K0: transpose+convert weights to bf16 [n][k]; wqk = wq-wk; zero sums ----------
__global__ __launch_bounds__(256) void k0_kernel(
    const float* __restrict__ wq, const float* __restrict__ wk,
    const float* __restrict__ fc1_w, const float* __restrict__ fc2_w,
    const float* __restrict__ d2_w, const float* __restrict__ g1_w,
    const float* __restrict__ g2_w, const float* __restrict__ wv_w,
    float* __restrict__ sums,
    short* __restrict__ d2t, short* __restrict__ fc1t, short* __restrict__ wqkt,
    short* __restrict__ g1t, short* __restrict__ g2t, short* __restrict__ wvt,
    short* __restrict__ fc2t) {
  int t = threadIdx.x, bi = blockIdx.x;
  if (bi == 0) sums[t] = 0.f;                  // sums[BB*DM]
  int mat = bi >> 5, blk = bi & 31;
  if (mat == 1) {                              // fc1: [64][128] -> fc1t[128][64]
    int i = blk * 256 + t;
    int n = i >> 6, k = i & 63;
    fc1t[n * 64 + k] = (short)f2bf(fc1_w[k * 128 + n]);
  } else if (mat == 6) {                       // fc2: [128][64] -> fc2t[64][128]
    int i = blk * 256 + t;
    int n = i >> 7, k = i & 127;
    fc2t[n * 128 + k] = (short)f2bf(fc2_w[k * 64 + n]);
  } else {
    const float* src = (mat == 0) ? d2_w : (mat == 2) ? wq : (mat == 3) ? g1_w
                     : (mat == 4) ? g2_w : wv_w;
    short* dst = (mat == 0) ? d2t : (mat == 2) ? wqkt : (mat == 3) ? g1t
               : (mat == 4) ? g2t : wvt;
#pragma unroll
    for (int j = 0; j < 2; ++j) {
      int i = blk * 512 + t + j * 256;
      int n = i >> 7, k = i & 127;
      float v = src[k * 128 + n];
      if (mat == 2) v -= wk[k * 128 + n];
      dst[n * 128 + k] = (short)f2bf(v);
    }
  }
}

// ---------- per-wave register B strips ----------
template<int K>
__device__ __forceinline__ void loadB(const short* __restrict__ Wt,
                                      int wid, int col, int quad, short8v b[2][4]) {
#pragma unroll
  for (int nt = 0; nt < 2; ++nt)
#pragma unroll
    for (int kt = 0; kt < K / 32; ++kt)
      b[nt][kt] = *(const short8v*)(Wt + (wid * 32 + nt * 16 + col) * K + kt * 32 + quad * 8);
}

// M=32 tile: acc[2][2], A in LDS [32][136]
template<int K>
__device__ __forceinline__ void gemm_compute(const short* __restrict__ A,
                                             const short8v b[2][4],
                                             int col, int quad, float4v acc[2][2]) {
#pragma unroll
  for (int kt = 0; kt < K / 32; ++kt) {
#pragma unroll
    for (int mt = 0; mt < 2; ++mt) {
      short8v a = *(const short8v*)(A + (mt * 16 + col) * 136 + kt * 32 + quad * 8);
      acc[mt][0] = __builtin_amdgcn_mfma_f32_16x16x32_bf16(a, b[0][kt], acc[mt][0], 0, 0, 0);
      acc[mt][1] = __builtin_amdgcn_mfma_f32_16x16x32_bf16(a, b[1][kt], acc[mt][1], 0, 0, 0);
    }
  }
}

__device__ __forceinline__ void store_tile(short* __restrict__ dst,
                                           const float4v acc[2][2],
                                           int wid, int col, int quad,
                                           float b0, float b1, bool do_relu) {
#pragma unroll
  for (int mt = 0; mt < 2; ++mt)
#pragma unroll
    for (int nt = 0; nt < 2; ++nt) {
      float bias = nt ? b1 : b0;
#pragma unroll
      for (int r = 0; r < 4; ++r) {
        float v = acc[mt][nt][r] + bias;
        if (do_relu) v = fmaxf(v, 0.f);
        dst[(mt * 16 + quad * 4 + r) * 136 + wid * 32 + nt * 16 + col] = (short)f2bf(v);
      }
    }
}

#define ZERO_ACC(acc) \
  _Pragma("unroll") for (int mt = 0; mt < 2; ++mt) \
  _Pragma("unroll") for (int nt = 0; nt < 2; ++nt) \
  _Pragma("unroll") for (int r = 0; r < 4; ++r) acc[mt][nt][r] = 0.f;

#define COPY_ACC(dst, src) \
  _Pragma("unroll") for (int mt = 0; mt < 2; ++mt) \
  _Pragma("unroll") for (int nt = 0; nt < 2; ++nt) \
  _Pragma("unroll") for (int r = 0; r < 4; ++r) dst[mt][nt][r] = src[mt][nt][r];

// ---------- K1: persistent blocks; weights in regs across 8 tiles ----------
__global__ __launch_bounds__(256, 2) void k1_kernel(
    const float* __restrict__ xyz, const float* __restrict__ features,
    const short* __restrict__ fc1t, const float* __restrict__ fc1_b,
    const float* __restrict__ d1_w, const float* __restrict__ d1_b,
    const short* __restrict__ d2t, const float* __restrict__ d2_b,
    const short* __restrict__ g1t, const float* __restrict__ g1_b,
    const short* __restrict__ g2t, const float* __restrict__ g2_b,
    const short* __restrict__ wqkt, const short* __restrict__ wvt,
    unsigned short* __restrict__ Ebf, unsigned short* __restrict__ Gbf,
    float* __restrict__ sums) {
  __shared__ __align__(16) short As[32 * 136];   // R -> F -> T -> H
  __shared__ __align__(16) short Xs[32 * 136];   // xyz scratch, then X

  const int tid = threadIdx.x;
  const int wid = tid >> 6, lane = tid & 63;
  const int col = lane & 15, quad = lane >> 4;
  const int bk = blockIdx.x;
  const int bi = bk >> 8;                        // blocks 0..255 batch0, 256..511 batch1
  const int ch0 = wid * 32 + col, ch1 = ch0 + 16;

  // hoisted B strips (5 x 32 VGPR) — loaded ONCE per block
  short8v Bd2[2][4], Bqk[2][4], Bg1[2][4], Bg2[2][4], Bwv[2][4];
  loadB<128>(d2t, wid, col, quad, Bd2);
  loadB<128>(wqkt, wid, col, quad, Bqk);
  loadB<128>(g1t, wid, col, quad, Bg1);
  loadB<128>(g2t, wid, col, quad, Bg2);
  loadB<128>(wvt, wid, col, quad, Bwv);

  const float d2b0 = d2_b[ch0], d2b1 = d2_b[ch1];
  const float f1b0 = fc1_b[ch0], f1b1 = fc1_b[ch1];
  const float g1b0 = g1_b[ch0], g1b1 = g1_b[ch1];
  const float g2b0 = g2_b[ch0], g2b1 = g2_b[ch1];

  float s0 = 0.f, s1 = 0.f;                      // exp-sum accumulators across tiles
  float* xf = (float*)Xs;

  for (int it = 0; it < K1_ITERS; ++it) {
    const long long p0 = ((long long)bk * K1_ITERS + it) * 32;

    // prefetch this tile's inputs into regs (drained by next barrier = hidden)
    float xr = 0.f;
    if (tid < 96) xr = xyz[p0 * 3 + tid];
    float4 f0 = *(const float4*)(features + p0 * 64 + (long long)tid * 4);
    float4 f1 = *(const float4*)(features + p0 * 64 + (long long)(tid + 256) * 4);
    short8v Bf1[2][4];
    loadB<64>(fc1t, wid, col, quad, Bf1);

    __syncthreads();                             // (0) prev iter's As/Xs readers done
    if (tid < 96) xf[tid] = xr;
    __syncthreads();                             // (1) xyz visible

    // R = relu(xyz @ d1 + d1_b) -> As
    {
      const int tn = tid & 31, tm = tid >> 5;
      const int c4 = tn * 4, pbase = tm * 4;
      float4 w0 = *(const float4*)(d1_w + c4);
      float4 w1 = *(const float4*)(d1_w + 128 + c4);
      float4 w2 = *(const float4*)(d1_w + 256 + c4);
      float4 bb = *(const float4*)(d1_b + c4);
#pragma unroll
      for (int p = 0; p < 4; ++p) {
        float x0 = xf[(pbase + p) * 3 + 0];
        float x1 = xf[(pbase + p) * 3 + 1];
        float x2 = xf[(pbase + p) * 3 + 2];
        short4 rr;
        rr.x = (short)f2bf(fmaxf(0.f, fmaf(x0, w0.x, fmaf(x1, w1.x, fmaf(x2, w2.x, bb.x)))));
        rr.y = (short)f2bf(fmaxf(0.f, fmaf(x0, w0.y, fmaf(x1, w1.y, fmaf(x2, w2.y, bb.y)))));
        rr.z = (short)f2bf(fmaxf(0.f, fmaf(x0, w0.z, fmaf(x1, w1.z, fmaf(x2, w2.z, bb.z)))));
        rr.w = (short)f2bf(fmaxf(0.f, fmaf(x0, w0.w, fmaf(x1, w1.w, fmaf(x2, w2.w, bb.w)))));
        *(short4*)(As + (pbase + p) * 136 + c4) = rr;
      }
    }
    __syncthreads();                             // (2) R written

    float4v pe[2][2], acc[2][2];

    // PE = R @ d2 + d2_b (regs)
    ZERO_ACC(acc)
    gemm_compute<128>(As, Bd2, col, quad, acc);
#pragma unroll
    for (int mt = 0; mt < 2; ++mt)
#pragma unroll
      for (int r = 0; r < 4; ++r) {
        pe[mt][0][r] = acc[mt][0][r] + d2b0;
        pe[mt][1][r] = acc[mt][1][r] + d2b1;
      }
    __syncthreads();                             // (3) d2's As readers done

    // F (from prefetched regs) -> As
    {
      int c = tid, row = c >> 4, cp = (c & 15) * 4;
      short4 s;
      s.x = (short)f2bf(f0.x); s.y = (short)f2bf(f0.y);
      s.z = (short)f2bf(f0.z); s.w = (short)f2bf(f0.w);
      *(short4*)(As + row * 136 + cp) = s;
      c = tid + 256; row = c >> 4; cp = (c & 15) * 4;
      s.x = (short)f2bf(f1.x); s.y = (short)f2bf(f1.y);
      s.z = (short)f2bf(f1.z); s.w = (short)f2bf(f1.w);
      *(short4*)(As + row * 136 + cp) = s;
    }
    __syncthreads();                             // (4) F written

    // X = F @ fc1 + fc1_b -> Xs
    ZERO_ACC(acc)
    gemm_compute<64>(As, Bf1, col, quad, acc);
    store_tile(Xs, acc, wid, col, quad, f1b0, f1b1, false);
    __syncthreads();                             // (5) Xs written; As(F) reads done

    // T = PE + X @ wqk -> As
    COPY_ACC(acc, pe)
    gemm_compute<128>(Xs, Bqk, col, quad, acc);
    store_tile(As, acc, wid, col, quad, 0.f, 0.f, false);
    __syncthreads();                             // (6) T written

    // H = relu(T @ g1 + g1_b) -> As (in place)
    ZERO_ACC(acc)
    gemm_compute<128>(As, Bg1, col, quad, acc);
    __syncthreads();                             // (7) T readers done
    store_tile(As, acc, wid, col, quad, g1b0, g1b1, true);
    __syncthreads();                             // (8) H written

    // L = H @ g2 + g2_b; E = exp(L*SCALE) -> global bf16; sums in regs
    ZERO_ACC(acc)
    gemm_compute<128>(As, Bg2, col, quad, acc);
#pragma unroll
    for (int mt = 0; mt < 2; ++mt)
#pragma unroll
      for (int r = 0; r < 4; ++r) {
        long long row = p0 + mt * 16 + quad * 4 + r;
        float e0 = __expf((acc[mt][0][r] + g2b0) * SCALEF);
        float e1 = __expf((acc[mt][1][r] + g2b1) * SCALEF);
        Ebf[row * DM + ch0] = f2bf(e0);
        Ebf[row * DM + ch1] = f2bf(e1);
        s0 += e0; s1 += e1;
      }

    // G = PE + X @ wv -> global bf16 (Xs untouched since (5))
    COPY_ACC(acc, pe)
    gemm_compute<128>(Xs, Bwv, col, quad, acc);
#pragma unroll
    for (int mt = 0; mt < 2; ++mt)
#pragma unroll
      for (int r = 0; r < 4; ++r) {
        long long row = p0 + mt * 16 + quad * 4 + r;
        Gbf[row * DM + ch0] = f2bf(acc[mt][0][r]);
        Gbf[row * DM + ch1] = f2bf(acc[mt][1][r]);
      }
  }

  // one reduced atomic per channel per block (256 blocks/address total)
  s0 += __shfl_xor(s0, 16, 64); s0 += __shfl_xor(s0, 32, 64);
  s1 += __shfl_xor(s1, 16, 64); s1 += __shfl_xor(s1, 32, 64);
  if (quad == 0) {
    atomicAdd(&sums[bi * DM + ch0], s0);
    atomicAdd(&sums[bi * DM + ch1], s1);
  }
}

// ---------- K3: persistent; attn = E/sum; res = bf16(attn*G) @ fc2 + fc2_b + features ----------
// Gbf aliases the res output region byte-exactly; each block reads its own tile's G
// before overwriting that tile's res (within-block ordering via barriers).
__global__ __launch_bounds__(256, 2) void k3_kernel(
    const unsigned short* __restrict__ Ebf, float* __restrict__ out_attn,
    float* __restrict__ out_res, const unsigned short* __restrict__ Gbf,
    const float* __restrict__ sums,
    const short* __restrict__ fc2t, const float* __restrict__ fc2_b,
    const float* __restrict__ features) {
  __shared__ __align__(16) short Ys[32 * 136];   // bf16 Y; reused as float[32][68]
  const int tid = threadIdx.x;
  const int bk = blockIdx.x;
  const int bi = bk >> 8;

  // hoisted: fc2 B strip (16 VGPR), bias, reciprocal sums
  const int wid = tid >> 6, lane = tid & 63;
  const int col = lane & 15, quad = lane >> 4;
  const int n = wid * 16 + col;
  short8v bw[4];
#pragma unroll
  for (int kt = 0; kt < 4; ++kt)
    bw[kt] = *(const short8v*)(fc2t + n * DM + kt * 32 + quad * 8);
  const float bb = fc2_b[n];

  const int tn = tid & 15, tm = tid >> 4;
  const int c8 = tn * 8;
  float4 sv0 = *(const float4*)(sums + bi * DM + c8);
  float4 sv1 = *(const float4*)(sums + bi * DM + c8 + 4);
  float4 r0, r1;
  r0.x = 1.f / sv0.x; r0.y = 1.f / sv0.y; r0.z = 1.f / sv0.z; r0.w = 1.f / sv0.w;
  r1.x = 1.f / sv1.x; r1.y = 1.f / sv1.y; r1.z = 1.f / sv1.z; r1.w = 1.f / sv1.w;

  for (int it = 0; it < K3_ITERS; ++it) {
    const long long p0 = ((long long)bk * K3_ITERS + it) * 32;

    // prefetch features for the res phase
    int fidx = tid, frow = fidx >> 4, fch = fidx & 15;
    float4 ft0 = *(const float4*)(features + (p0 + frow) * DP + fch * 4);
    int fidx1 = tid + 256, frow1 = fidx1 >> 4, fch1 = fidx1 & 15;
    float4 ft1 = *(const float4*)(features + (p0 + frow1) * DP + fch1 * 4);

    __syncthreads();                             // (0) prev iter's Ys users done

    // Phase A: normalize E -> attn (fp32, coalesced), Y = attn*G -> Ys bf16
#pragma unroll
    for (int it2 = 0; it2 < 2; ++it2) {
      int row = tm + it2 * 16;
      long long idx = (p0 + row) * DM + c8;
      short8v e8 = *(const short8v*)(Ebf + idx);
      short8v g8 = *(const short8v*)(Gbf + idx);
      float a[8];
      a[0] = bf2f((unsigned short)e8[0]) * r0.x; a[1] = bf2f((unsigned short)e8[1]) * r0.y;
      a[2] = bf2f((unsigned short)e8[2]) * r0.z; a[3] = bf2f((unsigned short)e8[3]) * r0.w;
      a[4] = bf2f((unsigned short)e8[4]) * r1.x; a[5] = bf2f((unsigned short)e8[5]) * r1.y;
      a[6] = bf2f((unsigned short)e8[6]) * r1.z; a[7] = bf2f((unsigned short)e8[7]) * r1.w;
      float4 a0 = {a[0], a[1], a[2], a[3]};
      float4 a1 = {a[4], a[5], a[6], a[7]};
      *(float4*)(out_attn + idx) = a0;
      *(float4*)(out_attn + idx + 4) = a1;
      short8v y;
#pragma unroll
      for (int q = 0; q < 8; ++q)
        y[q] = (short)f2bf(a[q] * bf2f((unsigned short)g8[q]));
      *(short8v*)(Ys + row * 136 + c8) = y;
    }
    __syncthreads();                             // (1) Y visible

    float4v acc[2];
#pragma unroll
    for (int mt = 0; mt < 2; ++mt)
#pragma unroll
      for (int r = 0; r < 4; ++r) acc[mt][r] = 0.f;
#pragma unroll
    for (int kt = 0; kt < 4; ++kt)
#pragma unroll
      for (int mt = 0; mt < 2; ++mt) {
        short8v a = *(const short8v*)(Ys + (mt * 16 + col) * 136 + kt * 32 + quad * 8);
        acc[mt] = __builtin_amdgcn_mfma_f32_16x16x32_bf16(a, bw[kt], acc[mt], 0, 0, 0);
      }
    __syncthreads();                             // (2) Ys reads done
    float* yf = (float*)Ys;                      // reuse as float[32][68]
#pragma unroll
    for (int mt = 0; mt < 2; ++mt)
#pragma unroll
      for (int r = 0; r < 4; ++r)
        yf[(mt * 16 + quad * 4 + r) * 68 + n] = acc[mt][r] + bb;
    __syncthreads();                             // (3) res tile in LDS

    // coalesced res store + features residual
    {
      float4 v = *(const float4*)(yf + frow * 68 + fch * 4);
      float4 o;
      o.x = v.x + ft0.x; o.y = v.y + ft0.y; o.z = v.z + ft0.z; o.w = v.w + ft0.w;
      *(float4*)(out_res + (p0 + frow) * DP + fch * 4) = o;
      v = *(const float4*)(yf + frow1 * 68 + fch1 * 4);
      o.x = v.x + ft1.x; o.y = v.y + ft1.y; o.z = v.z + ft1.z; o.w = v.w + ft1.w;
      *(float4*)(out_res + (p0 + frow1) * DP + fch1 * 4) = o;
    }
  }
}

extern "C" void kernel_launch(void* const* d_in, const int* in_sizes, int n_in,
                              void* d_out, int out_size, void* d_ws, size_t ws_size,
                              hipStream_t stream) {
  const float* xyz      = (const float*)d_in[0];
  const float* features = (const float*)d_in[1];
  const float* fc1_w    = (const float*)d_in[2];
  const float* fc1_b    = (const float*)d_in[3];
  const float* fc2_w    = (const float*)d_in[4];
  const float* fc2_b    = (const float*)d_in[5];
  const float* d1_w     = (const float*)d_in[6];
  const float* d1_b     = (const float*)d_in[7];
  const float* d2_w     = (const float*)d_in[8];
  const float* d2_b     = (const float*)d_in[9];
  const float* g1_w     = (const float*)d_in[10];
  const float* g1_b     = (const float*)d_in[11];
  const float* g2_w     = (const float*)d_in[12];
  const float* g2_b     = (const float*)d_in[13];
  const float* wq       = (const float*)d_in[14];
  const float* wk       = (const float*)d_in[15];
  const float* wv       = (const float*)d_in[16];

  float* out_res  = (float*)d_out;
  float* out_attn = out_res + (long long)BB * NN * DP;

  float* sums = (float*)d_ws;                          // [256]
  short* d2t  = (short*)(sums + 256);                  // 128*128
  short* fc1t = d2t + 16384;                           // 128*64
  short* wqkt = fc1t + 8192;                           // 128*128
  short* g1t  = wqkt + 16384;
  short* g2t  = g1t + 16384;
  short* wvt  = g2t + 16384;
  short* fc2t = wvt + 16384;                           // 64*128
  unsigned short* Ebf = (unsigned short*)(fc2t + 8192);   // [BB*NN*DM] bf16 (~33.5 MB)
  unsigned short* Gbf = (unsigned short*)d_out;        // aliases res region (byte-exact)

  hipLaunchKernelGGL(k0_kernel, dim3(224), dim3(256), 0, stream,
                     wq, wk, fc1_w, fc2_w, d2_w, g1_w, g2_w, wv,
                     sums, d2t, fc1t, wqkt, g1t, g2t, wvt, fc2t);
  hipLaunchKernelGGL(k1_kernel, dim3(K1_GRID), dim3(256), 0, stream,
                     xyz, features, fc1t, fc1_b, d1_w, d1_b, d2t, d2_b,
                     g1t, g1_b, g2t, g2_b, wqkt, wvt, Ebf, Gbf, sums);
  hipLaunchKernelGGL(k3_kernel, dim3(K3_GRID), dim3(256), 0, stream,
                     Ebf, out_attn, out_res, Gbf, sums, fc2t, fc2_b, features);
}